// Round 4
// baseline (206.257 us; speedup 1.0000x reference)
//
#include <hip/hip_runtime.h>
#include <stdint.h>

// ---------------- problem constants ----------------
#define B_ROWS 65536
#define D_IN   784
#define H_DIM  256
#define L_LEAF 64
#define C_CLS  10
#define NSTEP  13            // ceil(784/64) K-steps of 64
#define BTILE  40960         // 320 n * 64 k * 2B per K-step tile
#define GAP_THRESH 0.03f     // ~12 sigma of bf16 logit-gap noise

using f32x4    = __attribute__((ext_vector_type(4))) float;
using bf16x8   = __attribute__((ext_vector_type(8))) short;
using ushort8v = __attribute__((ext_vector_type(8))) unsigned short;
using ushort4v = __attribute__((ext_vector_type(4))) unsigned short;

// ---------------- ws layout (bytes) ----------------
#define O_FLAGCNT  0
#define O_CHOICES  4096
#define O_FLAGROWS (O_CHOICES + B_ROWS * 4)
#define O_WT       (O_FLAGROWS + B_ROWS * 4)
#define O_FEAT     (O_WT + NSTEP * BTILE)
#define O_WLB      (O_FEAT + (size_t)B_ROWS * H_DIM * 2)
#define WS_BASE    O_WLB
#define WS_FULL    (O_WLB + (size_t)L_LEAF * H_DIM * C_CLS * 2)

__device__ __forceinline__ unsigned short f2bf(float f) {
    union { float f; unsigned int u; } c; c.f = f;
    unsigned int u = c.u;
    return (unsigned short)((u + 0x7fffu + ((u >> 16) & 1u)) >> 16);   // RNE
}
__device__ __forceinline__ float bf2f(unsigned short u) {
    union { unsigned int u; float f; } c; c.u = ((unsigned int)u) << 16;
    return c.f;
}
__device__ __forceinline__ unsigned int cvtpk(float a, float b) {
    unsigned int r;
    asm("v_cvt_pk_bf16_f32 %0, %1, %2" : "=v"(r) : "v"(a), "v"(b));   // RNE pack
    return r;
}

__device__ __forceinline__ void gload_lds16(const void* g, void* l) {
    __builtin_amdgcn_global_load_lds(
        (const __attribute__((address_space(1))) unsigned int*)g,
        (__attribute__((address_space(3))) unsigned int*)l, 16, 0, 0);
}

// ---------------- K0: build swizzled B image. ----------------
// Image byte (ts*40960 + n*128 + c4*16) holds 8 bf16 of column n,
// k = ts*64 + (c4 ^ (n&7))*8 .. +8   (zero-padded past 784).
__global__ void k0_prep(const float* __restrict__ Wf, const float* __restrict__ Wr,
                        unsigned short* __restrict__ Wt, unsigned int* __restrict__ flagcnt) {
    if (blockIdx.x == 0 && threadIdx.x == 0) *flagcnt = 0u;
    int id = blockIdx.x * 256 + threadIdx.x;   // 33280 chunks total
    int ts = id / 2560;
    int r  = id % 2560;
    int n  = r % 320;
    int c4 = r / 320;
    int ks = ts * 64 + ((c4 ^ (n & 7)) << 3);
    unsigned short v[8];
    #pragma unroll
    for (int j = 0; j < 8; ++j) {
        int k = ks + j;
        float f = 0.f;
        if (k < D_IN)
            f = (n < H_DIM) ? Wf[(size_t)k * H_DIM + n]
                            : Wr[(size_t)k * L_LEAF + (n - H_DIM)];
        v[j] = f2bf(f);
    }
    *(ushort8v*)((char*)Wt + (size_t)ts * BTILE + (size_t)(n * 8 + c4) * 16) = *(ushort8v*)v;
}

// ---------------- K0b: Wl -> bf16 (optional, if ws permits) ----------------
__global__ void k0b_wl(const float* __restrict__ Wl, unsigned short* __restrict__ Wlb) {
    int i = (blockIdx.x * 256 + threadIdx.x) * 4;
    f32x4 v = *(const f32x4*)(Wl + i);
    ushort4v h; h.x = f2bf(v.x); h.y = f2bf(v.y); h.z = f2bf(v.z); h.w = f2bf(v.w);
    *(ushort4v*)(Wlb + i) = h;
}

// ---------------- K1: fused dual GEMM + argmax/flag ----------------
// grid = 1024 x 256 thr (4 waves). Wave = 64 rows x 80 cols (4 M-tiles x 5 N-tiles):
// 4:1 MFMA:ds_read. A reg-direct (4 rows/lane), B via gload_lds dbuf.
__global__ __launch_bounds__(256, 2) void k1_gemm(
    const float* __restrict__ x, const unsigned short* __restrict__ Wt,
    const float* __restrict__ bfv, const float* __restrict__ brv,
    unsigned short* __restrict__ feat, int* __restrict__ choices,
    unsigned int* __restrict__ flagcnt, int* __restrict__ flagrows)
{
    __shared__ __align__(16) unsigned short Bl[2][320 * 64];   // 2 x 40 KiB

    const int t = threadIdx.x, w = t >> 6, l = t & 63, q = l >> 4, ic = l & 15;
    const int bm0 = blockIdx.x * 64;
    const float* xbase = x + (size_t)(bm0 + ic) * D_IN;   // + mt*16 rows per fragment

    f32x4 acc[4][5];   // [mt][j]
    #pragma unroll
    for (int a = 0; a < 4; ++a)
        #pragma unroll
        for (int b = 0; b < 5; ++b)
            acc[a][b] = (f32x4){0.f, 0.f, 0.f, 0.f};

    // per-lane swizzled ds_read byte offsets (in shorts) within a 16-col slice
    const int rb0 = ic * 64 + (((q    ) ^ (ic & 7)) << 3);   // kk=0
    const int rb1 = ic * 64 + (((q + 4) ^ (ic & 7)) << 3);   // kk=1
    const int ntb = w * 5;                                    // wave's first N-tile

    // ---- prologue: stage ts=0, load A(ts=0)
    #pragma unroll
    for (int i = 0; i < 10; ++i) {
        int cid = i * 256 + t;
        gload_lds16((const char*)Wt + cid * 16, (char*)&Bl[0][0] + cid * 16);
    }
    f32x4 an[4][4];    // [mt][kk*2+half]
    #pragma unroll
    for (int mt = 0; mt < 4; ++mt) {
        const float* xr = xbase + (size_t)(mt * 16) * D_IN;
        #pragma unroll
        for (int kk = 0; kk < 2; ++kk) {
            int kg = kk * 32 + q * 8;
            an[mt][2 * kk]     = *(const f32x4*)(xr + kg);
            an[mt][2 * kk + 1] = *(const f32x4*)(xr + kg + 4);
        }
    }
    __syncthreads();

    int cur = 0;
    for (int ts = 0; ts < NSTEP; ++ts) {
        // ---- stage next B tile (in flight until barrier)
        if (ts + 1 < NSTEP) {
            const char* src = (const char*)Wt + (size_t)(ts + 1) * BTILE;
            char* dst = (char*)&Bl[cur ^ 1][0];
            #pragma unroll
            for (int i = 0; i < 10; ++i) {
                int cid = i * 256 + t;
                gload_lds16(src + cid * 16, dst + cid * 16);
            }
        }
        // ---- convert current A to bf16 fragments (frees an[])
        bf16x8 af[4][2];   // [mt][kk]
        #pragma unroll
        for (int mt = 0; mt < 4; ++mt) {
            #pragma unroll
            for (int kk = 0; kk < 2; ++kk) {
                union { unsigned int u[4]; bf16x8 v; } pk;
                f32x4 lo = an[mt][2 * kk], hi = an[mt][2 * kk + 1];
                pk.u[0] = cvtpk(lo.x, lo.y);
                pk.u[1] = cvtpk(lo.z, lo.w);
                pk.u[2] = cvtpk(hi.x, hi.y);
                pk.u[3] = cvtpk(hi.z, hi.w);
                af[mt][kk] = pk.v;
            }
        }
        // ---- prefetch A for ts+1
        if (ts + 1 < NSTEP) {
            #pragma unroll
            for (int mt = 0; mt < 4; ++mt) {
                const float* xr = xbase + (size_t)(mt * 16) * D_IN;
                #pragma unroll
                for (int kk = 0; kk < 2; ++kk) {
                    int kg = (ts + 1) * 64 + kk * 32 + q * 8;
                    if (kg + 8 <= D_IN) {
                        an[mt][2 * kk]     = *(const f32x4*)(xr + kg);
                        an[mt][2 * kk + 1] = *(const f32x4*)(xr + kg + 4);
                    } else {
                        an[mt][2 * kk]     = (f32x4){0.f, 0.f, 0.f, 0.f};
                        an[mt][2 * kk + 1] = (f32x4){0.f, 0.f, 0.f, 0.f};
                    }
                }
            }
        }
        // ---- MFMA: 2 kk x 5 j x 4 mt (each B frag reused 4x)
        const unsigned short* Bc = &Bl[cur][0];
        #pragma unroll
        for (int j = 0; j < 5; ++j) {
            bf16x8 b = *(const bf16x8*)(Bc + (ntb + j) * 1024 + rb0);
            #pragma unroll
            for (int mt = 0; mt < 4; ++mt)
                acc[mt][j] = __builtin_amdgcn_mfma_f32_16x16x32_bf16(af[mt][0], b, acc[mt][j], 0, 0, 0);
        }
        #pragma unroll
        for (int j = 0; j < 5; ++j) {
            bf16x8 b = *(const bf16x8*)(Bc + (ntb + j) * 1024 + rb1);
            #pragma unroll
            for (int mt = 0; mt < 4; ++mt)
                acc[mt][j] = __builtin_amdgcn_mfma_f32_16x16x32_bf16(af[mt][1], b, acc[mt][j], 0, 0, 0);
        }
        __syncthreads();
        cur ^= 1;
    }

    // ---- epilogue: features (cols < 256)
    #pragma unroll
    for (int j = 0; j < 5; ++j) {
        int col = (ntb + j) * 16 + ic;
        if (col < H_DIM) {
            float bias = bfv[col];
            #pragma unroll
            for (int mt = 0; mt < 4; ++mt) {
                #pragma unroll
                for (int i = 0; i < 4; ++i) {
                    int row = bm0 + mt * 16 + q * 4 + i;
                    float v = acc[mt][j][i] + bias;
                    v = v > 0.f ? v : 0.f;
                    feat[(size_t)row * H_DIM + col] = f2bf(v);
                }
            }
        }
    }
    // ---- router: wave 3 holds cols 256..319 in j=1..4
    if (w == 3) {
        #pragma unroll
        for (int mt = 0; mt < 4; ++mt) {
            #pragma unroll
            for (int i = 0; i < 4; ++i) {
                float m1 = -1e30f, m2 = -1e30f;
                int a1 = 0;
                #pragma unroll
                for (int j = 1; j < 5; ++j) {
                    int leaf = (j - 1) * 16 + ic;
                    float v = acc[mt][j][i] + brv[leaf];
                    if (v > m1) { m2 = m1; m1 = v; a1 = leaf; }
                    else if (v > m2) { m2 = v; }
                }
                #pragma unroll
                for (int s = 1; s < 16; s <<= 1) {
                    float om1 = __shfl_xor(m1, s, 64);
                    float om2 = __shfl_xor(m2, s, 64);
                    int   oa1 = __shfl_xor(a1, s, 64);
                    bool take = (om1 > m1) || (om1 == m1 && oa1 < a1);
                    float nm2 = take ? fmaxf(om2, m1) : fmaxf(m2, om1);
                    m1 = take ? om1 : m1;
                    a1 = take ? oa1 : a1;
                    m2 = nm2;
                }
                if (ic == 0) {
                    int row = bm0 + mt * 16 + q * 4 + i;
                    choices[row] = a1;
                    if (m1 - m2 < GAP_THRESH) {
                        unsigned int idx = atomicAdd(flagcnt, 1u);
                        flagrows[idx] = row;
                    }
                }
            }
        }
    }
}

// ---------------- K2: exact fp32 router, Wr tiles shared via LDS ----------------
__global__ __launch_bounds__(256) void k2_exact(
    const float* __restrict__ x, const float* __restrict__ Wr,
    const float* __restrict__ brv, const unsigned int* __restrict__ flagcnt,
    const int* __restrict__ flagrows, int* __restrict__ choices)
{
    __shared__ float wl[64 * 64];   // [kk][l]
    __shared__ float xl[4][64];
    const unsigned int cnt = *flagcnt;
    const int t = threadIdx.x, w = t >> 6, l = t & 63;
    for (unsigned int base = blockIdx.x * 4u; base < cnt; base += gridDim.x * 4u) {
        unsigned int ri = base + w;
        int row = (ri < cnt) ? flagrows[ri] : 0;
        const float* xr = x + (size_t)row * D_IN;
        float s0 = 0.f, s1 = 0.f, s2 = 0.f, s3 = 0.f;
        for (int kt = 0; kt < NSTEP; ++kt) {
            int k0 = kt * 64;
            #pragma unroll
            for (int i = 0; i < 4; ++i) {
                int flat = i * 256 + t;
                int kk = flat >> 4, lq = (flat & 15) * 4;
                int kg = k0 + kk;
                f32x4 v = (f32x4){0.f, 0.f, 0.f, 0.f};
                if (kg < D_IN) v = *(const f32x4*)(Wr + (size_t)kg * L_LEAF + lq);
                *(f32x4*)&wl[kk * 64 + lq] = v;
            }
            xl[w][l] = (k0 + l < D_IN) ? xr[k0 + l] : 0.f;
            __syncthreads();
            #pragma unroll
            for (int kk = 0; kk < 64; kk += 4) {
                s0 = fmaf(xl[w][kk    ], wl[(kk    ) * 64 + l], s0);
                s1 = fmaf(xl[w][kk + 1], wl[(kk + 1) * 64 + l], s1);
                s2 = fmaf(xl[w][kk + 2], wl[(kk + 2) * 64 + l], s2);
                s3 = fmaf(xl[w][kk + 3], wl[(kk + 3) * 64 + l], s3);
            }
            __syncthreads();
        }
        float v = (s0 + s1) + (s2 + s3) + brv[l];
        int a = l;
        #pragma unroll
        for (int st = 1; st < 64; st <<= 1) {
            float ov = __shfl_xor(v, st, 64);
            int   oa = __shfl_xor(a, st, 64);
            if (ov > v || (ov == v && oa < a)) { v = ov; a = oa; }
        }
        if (l == 0 && ri < cnt) choices[row] = a;
    }
}

// ---------------- K3: per-row leaf matvec ----------------
__global__ __launch_bounds__(256) void k3_leaf(
    const unsigned short* __restrict__ feat, const int* __restrict__ choices,
    const float* __restrict__ Wl, const unsigned short* __restrict__ Wlb,
    const float* __restrict__ blv, float* __restrict__ out)
{
    const int t = threadIdx.x, wv = t >> 6, l = t & 63, g = l >> 4, i = l & 15;
    const int row = blockIdx.x * 16 + wv * 4 + g;
    const int leaf = choices[row];

    ushort8v f0 = *(const ushort8v*)(feat + (size_t)row * H_DIM + i * 16);
    ushort8v f1 = *(const ushort8v*)(feat + (size_t)row * H_DIM + i * 16 + 8);
    float fv[16];
    #pragma unroll
    for (int j = 0; j < 8; ++j) { fv[j] = bf2f(f0[j]); fv[8 + j] = bf2f(f1[j]); }

    float acc[C_CLS];
    #pragma unroll
    for (int c = 0; c < C_CLS; ++c) acc[c] = 0.f;

    if (Wlb) {
        const unsigned short* wp = Wlb + ((size_t)leaf * H_DIM + i * 16) * C_CLS;
        ushort8v wreg[20];
        #pragma unroll
        for (int j = 0; j < 20; ++j) wreg[j] = *(const ushort8v*)(wp + j * 8);
        #pragma unroll
        for (int h = 0; h < 16; ++h) {
            #pragma unroll
            for (int c = 0; c < C_CLS; ++c) {
                int e = h * C_CLS + c;
                acc[c] = fmaf(fv[h], bf2f(wreg[e >> 3][e & 7]), acc[c]);
            }
        }
    } else {
        const float* wp = Wl + ((size_t)leaf * H_DIM + i * 16) * C_CLS;
        #pragma unroll
        for (int h = 0; h < 16; ++h) {
            #pragma unroll
            for (int c = 0; c < C_CLS; ++c)
                acc[c] = fmaf(fv[h], wp[h * C_CLS + c], acc[c]);
        }
    }
    #pragma unroll
    for (int st = 1; st < 16; st <<= 1) {
        #pragma unroll
        for (int c = 0; c < C_CLS; ++c) acc[c] += __shfl_xor(acc[c], st, 64);
    }
    if (i == 0) {
        #pragma unroll
        for (int c = 0; c < C_CLS; ++c)
            out[(size_t)row * C_CLS + c] = acc[c] + blv[leaf * C_CLS + c];
    }
}

// ---------------- launcher ----------------
extern "C" void kernel_launch(void* const* d_in, const int* in_sizes, int n_in,
                              void* d_out, int out_size, void* d_ws, size_t ws_size,
                              hipStream_t stream) {
    if (ws_size < WS_BASE) return;   // loud fail
    const bool use_bf = ws_size >= WS_FULL;

    const float* x   = (const float*)d_in[0];
    const float* Wf  = (const float*)d_in[1];
    const float* bfv = (const float*)d_in[2];
    const float* Wr  = (const float*)d_in[3];
    const float* brv = (const float*)d_in[4];
    const float* Wl  = (const float*)d_in[5];
    const float* blv = (const float*)d_in[6];
    float* out = (float*)d_out;

    char* ws = (char*)d_ws;
    unsigned int*   flagcnt  = (unsigned int*)(ws + O_FLAGCNT);
    int*            choices  = (int*)(ws + O_CHOICES);
    int*            flagrows = (int*)(ws + O_FLAGROWS);
    unsigned short* Wt       = (unsigned short*)(ws + O_WT);
    unsigned short* feat     = (unsigned short*)(ws + O_FEAT);
    unsigned short* Wlb      = use_bf ? (unsigned short*)(ws + O_WLB) : (unsigned short*)0;

    hipLaunchKernelGGL(k0_prep, dim3(130), dim3(256), 0, stream, Wf, Wr, Wt, flagcnt);
    if (use_bf)
        hipLaunchKernelGGL(k0b_wl, dim3(160), dim3(256), 0, stream, Wl, Wlb);
    hipLaunchKernelGGL(k1_gemm, dim3(B_ROWS / 64), dim3(256), 0, stream,
                       x, Wt, bfv, brv, feat, choices, flagcnt, flagrows);
    hipLaunchKernelGGL(k2_exact, dim3(1024), dim3(256), 0, stream,
                       x, Wr, brv, flagcnt, flagrows, choices);
    hipLaunchKernelGGL(k3_leaf, dim3(B_ROWS / 16), dim3(256), 0, stream,
                       feat, choices, Wl, Wlb, blv, out);
}